// Round 1
// baseline (481.252 us; speedup 1.0000x reference)
//
#include <hip/hip_runtime.h>
#include <math.h>

// Problem constants (fixed by reference): B=4, D=H=W=48, Cin=Cout=24, modes 16/axis.
// Channel packing: q = c_chan*4 + c, c in 0..3 complex channels:
//   d_c = x[...,c] + i*x[...,7-c]   (c=0..3)
// Blade mapping (mv_ft concat order): bi<4 -> Re f_{bi}, bi>=4 -> Im f_{7-bi}.

#define TWO_PI_OVER_48 0.13089969389957471827f

#define BUILD_TW(tw)                                                         \
  do {                                                                       \
    int _t = threadIdx.x;                                                    \
    if (_t < 48) {                                                           \
      float _s, _c;                                                          \
      sincosf(-TWO_PI_OVER_48 * (float)_t, &_s, &_c);                        \
      (tw)[_t] = make_float2(_c, _s);                                        \
    }                                                                        \
    __syncthreads();                                                         \
  } while (0)

static __device__ __forceinline__ int freq_of(int m) { return (m < 8) ? m : (m + 32); }

// ---------------- forward stage 1: DFT over W (48 -> 16 modes) ----------------
// in : x[b][d][h][w][ci][comp]  (float)
// out: A[bdh][k3][q] (float2), bdh = b*2304+d*48+h
__global__ __launch_bounds__(192) void k_fwd_w(const float* __restrict__ x,
                                               float2* __restrict__ A) {
  __shared__ float xs[48 * 192];
  __shared__ float2 tw[48];
  {
    const float4* xp4 = (const float4*)(x + (size_t)blockIdx.x * 9216);
    float4* xs4 = (float4*)xs;
    for (int t = threadIdx.x; t < 2304; t += 192) xs4[t] = xp4[t];
  }
  BUILD_TW(tw);

  const int q = threadIdx.x % 96, half = threadIdx.x / 96;
  const int ci = q >> 2, c = q & 3;
  const int reo = ci * 8 + c, imo = ci * 8 + 7 - c;
  const int fbase = half * 40;  // k3 = half*8+r -> freq = r (half0) or 40+r (half1)

  float2 acc[8];
  int ph[8];
#pragma unroll
  for (int r = 0; r < 8; ++r) { acc[r] = make_float2(0.f, 0.f); ph[r] = 0; }

  for (int w = 0; w < 48; ++w) {
    const float zx = xs[w * 192 + reo];
    const float zy = xs[w * 192 + imo];
#pragma unroll
    for (int r = 0; r < 8; ++r) {
      const float2 t = tw[ph[r]];
      acc[r].x = fmaf(zx, t.x, acc[r].x); acc[r].x = fmaf(-zy, t.y, acc[r].x);
      acc[r].y = fmaf(zx, t.y, acc[r].y); acc[r].y = fmaf(zy, t.x, acc[r].y);
      ph[r] += fbase + r;
      if (ph[r] >= 48) ph[r] -= 48;
    }
  }
  float2* Ap = A + (size_t)blockIdx.x * (16 * 96);
#pragma unroll
  for (int r = 0; r < 8; ++r) Ap[(half * 8 + r) * 96 + q] = acc[r];
}

// ---------------- forward stage 2: DFT over H ----------------
// in : A[bd*48+h][k3][q]; out: Bv[(bd*16+k2)*16+k3][q]
__global__ __launch_bounds__(192) void k_fwd_h(const float2* __restrict__ A,
                                               float2* __restrict__ Bv) {
  __shared__ float2 tw[48];
  BUILD_TW(tw);
  const int k3 = blockIdx.x & 15, bd = blockIdx.x >> 4;
  const int q = threadIdx.x % 96, half = threadIdx.x / 96;
  const int fbase = half * 40;

  const float2* Ap = A + ((size_t)bd * 48 * 16 + k3) * 96 + q;  // + h*(16*96)
  float2 acc[8];
  int ph[8];
#pragma unroll
  for (int r = 0; r < 8; ++r) { acc[r] = make_float2(0.f, 0.f); ph[r] = 0; }

  for (int h = 0; h < 48; ++h) {
    const float2 z = Ap[(size_t)h * (16 * 96)];
#pragma unroll
    for (int r = 0; r < 8; ++r) {
      const float2 t = tw[ph[r]];
      acc[r].x = fmaf(z.x, t.x, acc[r].x); acc[r].x = fmaf(-z.y, t.y, acc[r].x);
      acc[r].y = fmaf(z.x, t.y, acc[r].y); acc[r].y = fmaf(z.y, t.x, acc[r].y);
      ph[r] += fbase + r;
      if (ph[r] >= 48) ph[r] -= 48;
    }
  }
  float2* Bp = Bv + ((size_t)bd * 256 + k3) * 96 + q;  // + k2*(16*96)
#pragma unroll
  for (int r = 0; r < 8; ++r) Bp[(size_t)(half * 8 + r) * (16 * 96)] = acc[r];
}

// ---------------- forward stage 3: DFT over D ----------------
// in : Bv[((b*48+d)*16+k2)*16+k3][q]; out: Cv[b*4096 + m1*256 + k23][q]
__global__ __launch_bounds__(192) void k_fwd_d(const float2* __restrict__ Bv,
                                               float2* __restrict__ Cv) {
  __shared__ float2 tw[48];
  BUILD_TW(tw);
  const int k23 = blockIdx.x & 255, b = blockIdx.x >> 8;
  const int q = threadIdx.x % 96, half = threadIdx.x / 96;
  const int fbase = half * 40;

  const float2* Bp = Bv + ((size_t)b * 48 * 256 + k23) * 96 + q;  // + d*(256*96)
  float2 acc[8];
  int ph[8];
#pragma unroll
  for (int r = 0; r < 8; ++r) { acc[r] = make_float2(0.f, 0.f); ph[r] = 0; }

  for (int d = 0; d < 48; ++d) {
    const float2 z = Bp[(size_t)d * (256 * 96)];
#pragma unroll
    for (int r = 0; r < 8; ++r) {
      const float2 t = tw[ph[r]];
      acc[r].x = fmaf(z.x, t.x, acc[r].x); acc[r].x = fmaf(-z.y, t.y, acc[r].x);
      acc[r].y = fmaf(z.x, t.y, acc[r].y); acc[r].y = fmaf(z.y, t.x, acc[r].y);
      ph[r] += fbase + r;
      if (ph[r] >= 48) ph[r] -= 48;
    }
  }
  float2* Cp = Cv + ((size_t)b * 4096 + k23) * 96 + q;  // + m1*(256*96)
#pragma unroll
  for (int r = 0; r < 8; ++r) Cp[(size_t)(half * 8 + r) * (256 * 96)] = acc[r];
}

// ---------------- einsum: per-mode 192x192 Clifford matmul ----------------
// in : Cv[b*4096+mode][q] (float2), wgt[8][24][24][4096]
// out: OMz[b*4096+mode][q] (float2), .x = blade c, .y = blade 7-c
__global__ __launch_bounds__(256) void k_einsum(const float2* __restrict__ Cv,
                                                const float* __restrict__ wgt,
                                                float2* __restrict__ OMz) {
  const int mode = blockIdx.x * 64 + (threadIdx.x & 63);
  const int co = blockIdx.y * 4 + (threadIdx.x >> 6);

  // kernel table: K[bo][bi] = SGN * w[WIDX]
  constexpr int WIDX[8][8] = {
      {0, 1, 2, 3, 4, 5, 6, 7}, {1, 0, 4, 5, 2, 3, 7, 6},
      {2, 4, 0, 6, 1, 7, 3, 5}, {3, 5, 6, 0, 7, 1, 2, 4},
      {4, 2, 1, 7, 0, 6, 5, 3}, {5, 3, 7, 1, 6, 0, 4, 2},
      {6, 7, 3, 2, 5, 4, 0, 1}, {7, 6, 5, 4, 3, 2, 1, 0}};
  constexpr int SGN[8][8] = {
      {1, 1, 1, 1, -1, -1, -1, -1}, {1, 1, -1, -1, 1, 1, -1, -1},
      {1, 1, 1, -1, -1, 1, 1, 1},   {1, 1, 1, 1, -1, -1, -1, -1},
      {1, 1, -1, 1, 1, -1, 1, 1},   {1, 1, -1, -1, 1, 1, -1, -1},
      {1, 1, 1, -1, -1, 1, 1, 1},   {1, 1, -1, 1, 1, -1, 1, 1}};

  float acc[8][4];
#pragma unroll
  for (int bo = 0; bo < 8; ++bo)
#pragma unroll
    for (int b = 0; b < 4; ++b) acc[bo][b] = 0.f;

  for (int ci = 0; ci < 24; ++ci) {
    float w8[8];
#pragma unroll
    for (int k = 0; k < 8; ++k)
      w8[k] = wgt[(size_t)((k * 24 + co) * 24 + ci) * 4096 + mode];
#pragma unroll
    for (int b = 0; b < 4; ++b) {
      const float4* cp =
          (const float4*)(Cv + ((size_t)(b * 4096 + mode) * 96 + ci * 4));
      const float4 u = cp[0], v = cp[1];
      const float inv[8] = {u.x, u.z, v.x, v.z, v.w, v.y, u.w, u.y};
#pragma unroll
      for (int bo = 0; bo < 8; ++bo) {
#pragma unroll
        for (int bi = 0; bi < 8; ++bi) {
          const float wv = w8[WIDX[bo][bi]];
          if (SGN[bo][bi] > 0)
            acc[bo][b] = fmaf(wv, inv[bi], acc[bo][b]);
          else
            acc[bo][b] = fmaf(wv, -inv[bi], acc[bo][b]);
        }
      }
    }
  }
#pragma unroll
  for (int b = 0; b < 4; ++b) {
    float2* op = OMz + ((size_t)(b * 4096 + mode) * 96 + co * 4);
#pragma unroll
    for (int c = 0; c < 4; ++c) op[c] = make_float2(acc[c][b], acc[7 - c][b]);
  }
}

// ---------------- inverse stage 1: iDFT over D (16 -> 48) ----------------
// in : OMz[b*4096 + m1*256 + k23][q]; out: IS1[((b*48+d)*16+k2)*16+k3][q]
__global__ __launch_bounds__(192) void k_inv_d(const float2* __restrict__ OMz,
                                               float2* __restrict__ IS1) {
  __shared__ float2 tw[48];
  BUILD_TW(tw);
  const int k23 = blockIdx.x & 255, b = blockIdx.x >> 8;
  const int q = threadIdx.x % 96, half = threadIdx.x / 96;
  const int d0 = half * 24;

  float2 zr[16];
#pragma unroll
  for (int m = 0; m < 16; ++m)
    zr[m] = OMz[((size_t)(b * 4096 + m * 256 + k23)) * 96 + q];

  int ph[16];
#pragma unroll
  for (int m = 0; m < 16; ++m) ph[m] = (freq_of(m) * d0) % 48;

  float2* Op = IS1 + ((size_t)b * 48 * 256 + k23) * 96 + q;  // + d*(256*96)
  for (int dd = 0; dd < 24; ++dd) {
    float2 acc = make_float2(0.f, 0.f);
#pragma unroll
    for (int m = 0; m < 16; ++m) {
      const float2 t = tw[ph[m]];  // use conj(t)
      acc.x = fmaf(zr[m].x, t.x, acc.x); acc.x = fmaf(zr[m].y, t.y, acc.x);
      acc.y = fmaf(zr[m].y, t.x, acc.y); acc.y = fmaf(-zr[m].x, t.y, acc.y);
      ph[m] += freq_of(m);
      if (ph[m] >= 48) ph[m] -= 48;
    }
    Op[(size_t)(d0 + dd) * (256 * 96)] = acc;
  }
}

// ---------------- inverse stage 2: iDFT over H ----------------
// in : IS1[((bd)*16+m2)*16+m3][q]; out: IS2[((bd)*48+h)*16+m3][q]
__global__ __launch_bounds__(192) void k_inv_h(const float2* __restrict__ IS1,
                                               float2* __restrict__ IS2) {
  __shared__ float2 tw[48];
  BUILD_TW(tw);
  const int m3 = blockIdx.x & 15, bd = blockIdx.x >> 4;
  const int q = threadIdx.x % 96, half = threadIdx.x / 96;
  const int h0 = half * 24;

  float2 zr[16];
#pragma unroll
  for (int m = 0; m < 16; ++m)
    zr[m] = IS1[(((size_t)bd * 16 + m) * 16 + m3) * 96 + q];

  int ph[16];
#pragma unroll
  for (int m = 0; m < 16; ++m) ph[m] = (freq_of(m) * h0) % 48;

  float2* Op = IS2 + ((size_t)bd * 48 * 16 + m3) * 96 + q;  // + h*(16*96)
  for (int hh = 0; hh < 24; ++hh) {
    float2 acc = make_float2(0.f, 0.f);
#pragma unroll
    for (int m = 0; m < 16; ++m) {
      const float2 t = tw[ph[m]];
      acc.x = fmaf(zr[m].x, t.x, acc.x); acc.x = fmaf(zr[m].y, t.y, acc.x);
      acc.y = fmaf(zr[m].y, t.x, acc.y); acc.y = fmaf(-zr[m].x, t.y, acc.y);
      ph[m] += freq_of(m);
      if (ph[m] >= 48) ph[m] -= 48;
    }
    Op[(size_t)(h0 + hh) * (16 * 96)] = acc;
  }
}

// ---------------- inverse stage 3: iDFT over W + writeout ----------------
// in : IS2[blk*16+m][q], blk = b*2304+d*48+h
// out: out[((blk*48+w)*24+co)*8+comp], comp=c -> Re, comp=7-c -> Im; * 1/48^3
__global__ __launch_bounds__(192) void k_inv_w(const float2* __restrict__ IS2,
                                               float* __restrict__ out) {
  __shared__ float2 tw[48];
  BUILD_TW(tw);
  const int blk = blockIdx.x;
  const int q = threadIdx.x % 96, half = threadIdx.x / 96;
  const int co = q >> 2, c = q & 3;
  const int w0 = half * 24;
  const float norm = 1.0f / 110592.0f;

  float2 zr[16];
#pragma unroll
  for (int m = 0; m < 16; ++m) zr[m] = IS2[((size_t)blk * 16 + m) * 96 + q];

  int ph[16];
#pragma unroll
  for (int m = 0; m < 16; ++m) ph[m] = (freq_of(m) * w0) % 48;

  for (int ww = 0; ww < 24; ++ww) {
    float2 acc = make_float2(0.f, 0.f);
#pragma unroll
    for (int m = 0; m < 16; ++m) {
      const float2 t = tw[ph[m]];
      acc.x = fmaf(zr[m].x, t.x, acc.x); acc.x = fmaf(zr[m].y, t.y, acc.x);
      acc.y = fmaf(zr[m].y, t.x, acc.y); acc.y = fmaf(-zr[m].x, t.y, acc.y);
      ph[m] += freq_of(m);
      if (ph[m] >= 48) ph[m] -= 48;
    }
    const size_t base = (size_t)(blk * 48 + (w0 + ww)) * 192 + co * 8;
    out[base + c] = acc.x * norm;
    out[base + 7 - c] = acc.y * norm;
  }
}

extern "C" void kernel_launch(void* const* d_in, const int* in_sizes, int n_in,
                              void* d_out, int out_size, void* d_ws, size_t ws_size,
                              hipStream_t stream) {
  (void)in_sizes; (void)n_in; (void)out_size;
  const float* x = (const float*)d_in[0];
  const float* wgt = (const float*)d_in[1];
  float* out = (float*)d_out;

  // Scratch placement (disjoint lifetimes inside d_out, 339.7 MB total):
  //   A   [0,          113246208)   fwd-W output     (live S1..S2)
  //   Bv  [113246208,  150994944)   fwd-H output     (live S2..S3)
  //   Cv  [150994944,  163577856)   fwd-D output     (live S3..E)
  //   OMz [163577856,  176160768)   einsum output    (live E..I1)
  //   IS1 [0,           37748736)   inv-D output     (live I1..I2, A dead)
  // IS2 (113 MB) must NOT alias d_out (inv-W reads it while writing the full
  // output) -> lives in d_ws. Requires ws_size >= 113246208.
  char* ob = (char*)d_out;
  float2* A   = (float2*)(ob + 0);
  float2* Bv  = (float2*)(ob + 113246208);
  float2* Cv  = (float2*)(ob + 150994944);
  float2* OMz = (float2*)(ob + 163577856);
  float2* IS1 = (float2*)(ob + 0);
  float2* IS2 = (float2*)d_ws;
  (void)ws_size;

  k_fwd_w<<<9216, 192, 0, stream>>>(x, A);
  k_fwd_h<<<3072, 192, 0, stream>>>(A, Bv);
  k_fwd_d<<<1024, 192, 0, stream>>>(Bv, Cv);
  k_einsum<<<dim3(64, 6), 256, 0, stream>>>(Cv, wgt, OMz);
  k_inv_d<<<1024, 192, 0, stream>>>(OMz, IS1);
  k_inv_h<<<3072, 192, 0, stream>>>(IS1, IS2);
  k_inv_w<<<9216, 192, 0, stream>>>(IS2, out);
}

// Round 2
// 351.156 us; speedup vs baseline: 1.3705x; 1.3705x over previous
//
#include <hip/hip_runtime.h>
#include <math.h>

// Clifford spectral conv: B=4, D=H=W=48, Cin=Cout=24, 16 modes/axis.
// q = ci*4 + c indexes 96 complex channels; d_c = x[...,c] + i*x[...,7-c].
// All DFT stages use radix-3 (48 = 3*16) + compile-time-constant twiddle
// recurrence in registers: NO LDS twiddle lookups, no integer phase tracking.

#define C866 0.8660254037844386f

// cos/sin(t*2pi/48) for t=0..7 (FC0/FS0) and t=40..47 (FC1/FS1)
constexpr float FC0[8] = {1.0f, 0.99144486137885f, 0.96592582628907f, 0.92387953251129f,
                          0.86602540378444f, 0.79335334029124f, 0.70710678118655f, 0.60876142900872f};
constexpr float FS0[8] = {0.0f, 0.13052619222005f, 0.25881904510252f, 0.38268343236509f,
                          0.5f, 0.60876142900872f, 0.70710678118655f, 0.79335334029124f};
constexpr float FC1[8] = {0.5f, 0.60876142900872f, 0.70710678118655f, 0.79335334029124f,
                          0.86602540378444f, 0.92387953251129f, 0.96592582628907f, 0.99144486137885f};
constexpr float FS1[8] = {-0.86602540378444f, -0.79335334029124f, -0.70710678118655f, -0.60876142900872f,
                          -0.5f, -0.38268343236509f, -0.25881904510252f, -0.13052619222005f};

__device__ __forceinline__ float2 cmul(float2 a, float2 b) {
  return make_float2(fmaf(a.x, b.x, -(a.y * b.y)), fmaf(a.x, b.y, a.y * b.x));
}
__device__ __forceinline__ void cfma(float2& acc, float2 a, float2 t) {
  acc.x = fmaf(a.x, t.x, acc.x); acc.x = fmaf(-a.y, t.y, acc.x);
  acc.y = fmaf(a.x, t.y, acc.y); acc.y = fmaf(a.y, t.x, acc.y);
}

// ---------------- forward DFT core: 48 inputs -> 8 modes (this thread's half)
// k = 40*half + r.  X[k] = sum_j e^{-i th k j} * y_{(half+r)%3}(j), j=0..15,
// y built from pre-rotated z' (z'_a = z_a * w3^(half*a), w3 = e^{-2pi i/3}).
struct FwdState {
  float2 acc[8], t[8], stp[8];
  float2 R1, R2;
};

__device__ __forceinline__ void fwd_init(FwdState& st, int half) {
#pragma unroll
  for (int r = 0; r < 8; ++r) {
    st.acc[r] = make_float2(0.f, 0.f);
    st.t[r] = make_float2(1.f, 0.f);
    st.stp[r] = make_float2(half ? FC1[r] : FC0[r],
                            half ? -FS1[r] : -FS0[r]);  // e^{-i th k}
  }
  st.R1 = half ? make_float2(-0.5f, -C866) : make_float2(1.f, 0.f);  // w3^half
  st.R2 = half ? make_float2(-0.5f,  C866) : make_float2(1.f, 0.f);  // w3^2half
}

__device__ __forceinline__ void fwd_stepf(FwdState& st, float2 z0, float2 z1, float2 z2) {
  z1 = cmul(z1, st.R1);
  z2 = cmul(z2, st.R2);
  const float sx = z1.x + z2.x, sy = z1.y + z2.y;
  const float dx = z1.x - z2.x, dy = z1.y - z2.y;
  const float2 y0 = make_float2(z0.x + sx, z0.y + sy);
  const float tx = fmaf(-0.5f, sx, z0.x), ty = fmaf(-0.5f, sy, z0.y);
  const float ex = C866 * dx, ey = C866 * dy;
  const float2 y1 = make_float2(tx + ey, ty - ex);  // z0 + w3 z1 + w3^2 z2
  const float2 y2 = make_float2(tx - ey, ty + ex);
#pragma unroll
  for (int r = 0; r < 8; ++r) {
    const float2 yy = (r % 3 == 0) ? y0 : ((r % 3 == 1) ? y1 : y2);
    cfma(st.acc[r], yy, st.t[r]);
    st.t[r] = cmul(st.t[r], st.stp[r]);
  }
}

// ---------------- inverse iDFT core: 16 modes -> 48 outputs
// out[j+16a] = sum_c u_c(j) * phi^{a c}, phi = e^{+2pi i/3};
// u_c(j) = sum_{m: f(m)%3==c} zr_m e^{+i th f(m) j}, f(m) = m<8 ? m : m+32.
struct InvState {
  float2 zr[16], t[16];
};

__device__ __forceinline__ void inv_init(InvState& st) {
#pragma unroll
  for (int m = 0; m < 16; ++m) st.t[m] = make_float2(1.f, 0.f);
}

__device__ __forceinline__ void inv_stepf(InvState& st, float2& o0, float2& o1, float2& o2) {
  constexpr int JG[16] = {0,1,2,0,1,2,0,1, 1,2,0,1,2,0,1,2};  // f(m) % 3
  float2 u0 = make_float2(0.f, 0.f), u1 = u0, u2 = u0;
#pragma unroll
  for (int m = 0; m < 16; ++m) {
    float2& uu = (JG[m] == 0) ? u0 : ((JG[m] == 1) ? u1 : u2);
    cfma(uu, st.zr[m], st.t[m]);
    const float2 stp = (m < 8) ? make_float2(FC0[m], FS0[m])
                               : make_float2(FC1[m - 8], FS1[m - 8]);  // e^{+i th f}
    st.t[m] = cmul(st.t[m], stp);
  }
  const float sx = u1.x + u2.x, sy = u1.y + u2.y;
  const float dx = u1.x - u2.x, dy = u1.y - u2.y;
  o0 = make_float2(u0.x + sx, u0.y + sy);
  const float tx = fmaf(-0.5f, sx, u0.x), ty = fmaf(-0.5f, sy, u0.y);
  const float ex = C866 * dx, ey = C866 * dy;
  o1 = make_float2(tx - ey, ty + ex);  // u0 + phi u1 + phi^2 u2
  o2 = make_float2(tx + ey, ty - ex);
}

// ---------------- forward stage 1: DFT over W ----------------
// in : x[b][d][h][w][ci][comp]; out: A[bdh][k3][q] (float2)
__global__ __launch_bounds__(192) void k_fwd_w(const float* __restrict__ x,
                                               float2* __restrict__ A) {
  __shared__ __align__(16) float2 xs[48 * 96];  // [w][q] complex-paired
  {
    const float* xp = x + (size_t)blockIdx.x * 9216;
    for (int idx = threadIdx.x; idx < 1152; idx += 192) {
      const int w = idx / 24, ci = idx % 24;
      const float4 u = *(const float4*)(xp + w * 192 + ci * 8);
      const float4 v = *(const float4*)(xp + w * 192 + ci * 8 + 4);
      float4* dst = (float4*)(&xs[w * 96 + ci * 4]);
      dst[0] = make_float4(u.x, v.w, u.y, v.z);
      dst[1] = make_float4(u.z, v.y, u.w, v.x);
    }
  }
  __syncthreads();

  const int q = threadIdx.x % 96, half = threadIdx.x / 96;
  FwdState st;
  fwd_init(st, half);
#pragma unroll 4
  for (int j = 0; j < 16; ++j) {
    const float2 z0 = xs[j * 96 + q];
    const float2 z1 = xs[(j + 16) * 96 + q];
    const float2 z2 = xs[(j + 32) * 96 + q];
    fwd_stepf(st, z0, z1, z2);
  }
  float2* Ap = A + (size_t)blockIdx.x * 1536 + q;
#pragma unroll
  for (int r = 0; r < 8; ++r) Ap[(half * 8 + r) * 96] = st.acc[r];
}

// ---------------- forward stage 2: DFT over H ----------------
// in : A[(bd*48+h)*16+k3][q]; out: Bv[(bd*256 + k2*16 + k3)][q]
__global__ __launch_bounds__(192) void k_fwd_h(const float2* __restrict__ A,
                                               float2* __restrict__ Bv) {
  const int k3 = blockIdx.x & 15, bd = blockIdx.x >> 4;
  const int q = threadIdx.x % 96, half = threadIdx.x / 96;
  const float2* Ap = A + ((size_t)bd * 768 + k3) * 96 + q;  // + h*1536
  FwdState st;
  fwd_init(st, half);
  for (int j = 0; j < 16; ++j) {
    const float2 z0 = Ap[(size_t)j * 1536];
    const float2 z1 = Ap[(size_t)(j + 16) * 1536];
    const float2 z2 = Ap[(size_t)(j + 32) * 1536];
    fwd_stepf(st, z0, z1, z2);
  }
  float2* Bp = Bv + ((size_t)bd * 256 + k3) * 96 + q;
#pragma unroll
  for (int r = 0; r < 8; ++r) Bp[(size_t)(half * 8 + r) * 1536] = st.acc[r];
}

// ---------------- forward stage 3: DFT over D ----------------
// in : Bv[(b*12288 + d*256 + k23)][q]; out: Cv[(b*4096 + m1*256 + k23)][q]
__global__ __launch_bounds__(192) void k_fwd_d(const float2* __restrict__ Bv,
                                               float2* __restrict__ Cv) {
  const int k23 = blockIdx.x & 255, b = blockIdx.x >> 8;
  const int q = threadIdx.x % 96, half = threadIdx.x / 96;
  const float2* Bp = Bv + ((size_t)b * 12288 + k23) * 96 + q;  // + d*24576
  FwdState st;
  fwd_init(st, half);
  for (int j = 0; j < 16; ++j) {
    const float2 z0 = Bp[(size_t)j * 24576];
    const float2 z1 = Bp[(size_t)(j + 16) * 24576];
    const float2 z2 = Bp[(size_t)(j + 32) * 24576];
    fwd_stepf(st, z0, z1, z2);
  }
  float2* Cp = Cv + ((size_t)b * 4096 + k23) * 96 + q;
#pragma unroll
  for (int r = 0; r < 8; ++r) Cp[(size_t)(half * 8 + r) * 24576] = st.acc[r];
}

// ---------------- einsum: per-mode 192x192 Clifford matmul ----------------
__global__ __launch_bounds__(256) void k_einsum(const float2* __restrict__ Cv,
                                                const float* __restrict__ wgt,
                                                float2* __restrict__ OMz) {
  const int mode = blockIdx.x * 64 + (threadIdx.x & 63);
  const int co = blockIdx.y * 4 + (threadIdx.x >> 6);

  constexpr int WIDX[8][8] = {
      {0, 1, 2, 3, 4, 5, 6, 7}, {1, 0, 4, 5, 2, 3, 7, 6},
      {2, 4, 0, 6, 1, 7, 3, 5}, {3, 5, 6, 0, 7, 1, 2, 4},
      {4, 2, 1, 7, 0, 6, 5, 3}, {5, 3, 7, 1, 6, 0, 4, 2},
      {6, 7, 3, 2, 5, 4, 0, 1}, {7, 6, 5, 4, 3, 2, 1, 0}};
  constexpr int SGN[8][8] = {
      {1, 1, 1, 1, -1, -1, -1, -1}, {1, 1, -1, -1, 1, 1, -1, -1},
      {1, 1, 1, -1, -1, 1, 1, 1},   {1, 1, 1, 1, -1, -1, -1, -1},
      {1, 1, -1, 1, 1, -1, 1, 1},   {1, 1, -1, -1, 1, 1, -1, -1},
      {1, 1, 1, -1, -1, 1, 1, 1},   {1, 1, -1, 1, 1, -1, 1, 1}};

  float acc[8][4];
#pragma unroll
  for (int bo = 0; bo < 8; ++bo)
#pragma unroll
    for (int b = 0; b < 4; ++b) acc[bo][b] = 0.f;

  for (int ci = 0; ci < 24; ++ci) {
    float w8[8];
#pragma unroll
    for (int k = 0; k < 8; ++k)
      w8[k] = wgt[(size_t)((k * 24 + co) * 24 + ci) * 4096 + mode];
#pragma unroll
    for (int b = 0; b < 4; ++b) {
      const float4* cp =
          (const float4*)(Cv + ((size_t)(b * 4096 + mode) * 96 + ci * 4));
      const float4 u = cp[0], v = cp[1];
      const float inv[8] = {u.x, u.z, v.x, v.z, v.w, v.y, u.w, u.y};
#pragma unroll
      for (int bo = 0; bo < 8; ++bo) {
#pragma unroll
        for (int bi = 0; bi < 8; ++bi) {
          const float wv = w8[WIDX[bo][bi]];
          if (SGN[bo][bi] > 0)
            acc[bo][b] = fmaf(wv, inv[bi], acc[bo][b]);
          else
            acc[bo][b] = fmaf(wv, -inv[bi], acc[bo][b]);
        }
      }
    }
  }
#pragma unroll
  for (int b = 0; b < 4; ++b) {
    float2* op = OMz + ((size_t)(b * 4096 + mode) * 96 + co * 4);
#pragma unroll
    for (int c = 0; c < 4; ++c) op[c] = make_float2(acc[c][b], acc[7 - c][b]);
  }
}

// ---------------- inverse stage 1: iDFT over D (16 -> 48) ----------------
// in : OMz[(b*4096 + m*256 + k23)][q]; out: IS1[(b*12288 + d*256 + k23)][q]
__global__ __launch_bounds__(192) void k_inv_d(const float2* __restrict__ OMz,
                                               float2* __restrict__ IS1) {
  const int col = blockIdx.x * 2 + threadIdx.x / 96;  // 1024 cols = (b, k23)
  const int q = threadIdx.x % 96;
  const int k23 = col & 255, b = col >> 8;
  InvState st;
#pragma unroll
  for (int m = 0; m < 16; ++m)
    st.zr[m] = OMz[((size_t)b * 4096 + m * 256 + k23) * 96 + q];
  inv_init(st);
  float2* Op = IS1 + ((size_t)b * 12288 + k23) * 96 + q;  // + d*24576
  for (int j = 0; j < 16; ++j) {
    float2 o0, o1, o2;
    inv_stepf(st, o0, o1, o2);
    Op[(size_t)j * 24576] = o0;
    Op[(size_t)(j + 16) * 24576] = o1;
    Op[(size_t)(j + 32) * 24576] = o2;
  }
}

// ---------------- inverse stage 2: iDFT over H ----------------
// in : IS1[(bd*256 + m*16 + m3)][q]; out: IS2[(bd*768 + h*16 + m3)][q]
__global__ __launch_bounds__(192) void k_inv_h(const float2* __restrict__ IS1,
                                               float2* __restrict__ IS2) {
  const int col = blockIdx.x * 2 + threadIdx.x / 96;  // 3072 cols = (bd, m3)
  const int q = threadIdx.x % 96;
  const int m3 = col & 15, bd = col >> 4;
  InvState st;
#pragma unroll
  for (int m = 0; m < 16; ++m)
    st.zr[m] = IS1[((size_t)bd * 256 + m * 16 + m3) * 96 + q];
  inv_init(st);
  float2* Op = IS2 + ((size_t)bd * 768 + m3) * 96 + q;  // + h*1536
  for (int j = 0; j < 16; ++j) {
    float2 o0, o1, o2;
    inv_stepf(st, o0, o1, o2);
    Op[(size_t)j * 1536] = o0;
    Op[(size_t)(j + 16) * 1536] = o1;
    Op[(size_t)(j + 32) * 1536] = o2;
  }
}

// ---------------- inverse stage 3: iDFT over W + writeout ----------------
// in : IS2[(blk*16 + m)][q]; out: out[(blk*48+w)*192 + co*8 + {c, 7-c}]
__global__ __launch_bounds__(192) void k_inv_w(const float2* __restrict__ IS2,
                                               float* __restrict__ out) {
  const int blk = blockIdx.x * 2 + threadIdx.x / 96;  // 9216 cols
  const int q = threadIdx.x % 96;
  const int co = q >> 2, c = q & 3;
  const float norm = 1.0f / 110592.0f;
  InvState st;
#pragma unroll
  for (int m = 0; m < 16; ++m) {
    float2 z = IS2[((size_t)blk * 16 + m) * 96 + q];
    st.zr[m] = make_float2(z.x * norm, z.y * norm);
  }
  inv_init(st);
  float* ob = out + (size_t)blk * 9216 + co * 8;
  for (int j = 0; j < 16; ++j) {
    float2 o0, o1, o2;
    inv_stepf(st, o0, o1, o2);
    float* p0 = ob + (size_t)j * 192;
    float* p1 = ob + (size_t)(j + 16) * 192;
    float* p2 = ob + (size_t)(j + 32) * 192;
    p0[c] = o0.x; p0[7 - c] = o0.y;
    p1[c] = o1.x; p1[7 - c] = o1.y;
    p2[c] = o2.x; p2[7 - c] = o2.y;
  }
}

extern "C" void kernel_launch(void* const* d_in, const int* in_sizes, int n_in,
                              void* d_out, int out_size, void* d_ws, size_t ws_size,
                              hipStream_t stream) {
  (void)in_sizes; (void)n_in; (void)out_size; (void)ws_size;
  const float* x = (const float*)d_in[0];
  const float* wgt = (const float*)d_in[1];
  float* out = (float*)d_out;

  // Scratch placement (disjoint lifetimes inside d_out, 339.7 MB total):
  //   A   [0,          113246208)   fwd-W output
  //   Bv  [113246208,  150994944)   fwd-H output
  //   Cv  [150994944,  163577856)   fwd-D output
  //   OMz [163577856,  176160768)   einsum output
  //   IS1 [0,           37748736)   inv-D output (A dead)
  // IS2 must not alias d_out (inv-W reads it while writing output) -> d_ws.
  char* ob = (char*)d_out;
  float2* A   = (float2*)(ob + 0);
  float2* Bv  = (float2*)(ob + 113246208);
  float2* Cv  = (float2*)(ob + 150994944);
  float2* OMz = (float2*)(ob + 163577856);
  float2* IS1 = (float2*)(ob + 0);
  float2* IS2 = (float2*)d_ws;

  k_fwd_w<<<9216, 192, 0, stream>>>(x, A);
  k_fwd_h<<<3072, 192, 0, stream>>>(A, Bv);
  k_fwd_d<<<1024, 192, 0, stream>>>(Bv, Cv);
  k_einsum<<<dim3(64, 6), 256, 0, stream>>>(Cv, wgt, OMz);
  k_inv_d<<<512, 192, 0, stream>>>(OMz, IS1);
  k_inv_h<<<1536, 192, 0, stream>>>(IS1, IS2);
  k_inv_w<<<4608, 192, 0, stream>>>(IS2, out);
}